// Round 5
// baseline (47.869 us; speedup 1.0000x reference)
//
#include <hip/hip_runtime.h>

#define IN_SIZE 11
#define HID 16
#define FEAT 18
#define TSTEPS 18

#define PACK_OFF 8192   // ints; first_arr occupies [0, B+1) padded to 8192

__device__ __forceinline__ float fast_rcp(float v) { return __builtin_amdgcn_rcpf(v); }

// broadcast a float from a fixed lane via v_readlane (SGPR path, no DS)
__device__ __forceinline__ float rl(float v, int lane) {
    return __int_as_float(__builtin_amdgcn_readlane(__float_as_int(v), lane));
}

// ---------------------------------------------------------------------------
// Kernel A: one coalesced int4 scan of batch[]. A rise batch[j-1] < batch[j]
// means first[v] = j for all v in (batch[j-1], batch[j]]. Each first[0..B]
// entry is written exactly once (rises partition the value space). The
// boundary-finding thread also copies that graph's first 18 edge ids / attrs
// into a packed per-graph buffer so the main kernel skips one latency round.
// ---------------------------------------------------------------------------
__global__ __launch_bounds__(256)
void scan_bounds(const int* __restrict__ batch,
                 const int* __restrict__ edge_index,
                 const int* __restrict__ edge_attr,
                 int* __restrict__ first_arr,
                 int* __restrict__ pack,
                 int E, int B)
{
    const int lane = threadIdx.x & 63;
    const int nthr = gridDim.x * blockDim.x;
    const int Q = E >> 2;                       // full int4 quads
    const int4* b4 = reinterpret_cast<const int4*>(batch);

    for (int q = blockIdx.x * blockDim.x + threadIdx.x; q < Q; q += nthr) {
        const int4 v = b4[q];
        const int i0 = q << 2;
        int prev = __shfl_up(v.w, 1, 64);       // lane l-1's last element = batch[i0-1]
        if (lane == 0) prev = (i0 == 0) ? -1 : batch[i0 - 1];

        const int pa[4] = {prev, v.x, v.y, v.z};
        const int pb[4] = {v.x,  v.y, v.z, v.w};
#pragma unroll
        for (int s = 0; s < 4; ++s) {
            if (pb[s] > pa[s]) {                // rare: ~4096 rises in 8M elements
                const int j0 = i0 + s;
                for (int g = pa[s] + 1; g <= pb[s]; ++g) {
                    first_arr[g] = j0;
                    if (g < B) {
                        int* pk = pack + g * 64;
#pragma unroll
                        for (int t = 0; t < TSTEPS; ++t) {
                            int jj = j0 + t; if (jj > E - 1) jj = E - 1;
                            pk[t]      = edge_index[jj];
                            pk[18 + t] = edge_index[E + jj];
                            pk[36 + t] = edge_attr[jj];
                        }
                    }
                }
            }
        }
    }

    // tail: values above batch[E-1] (incl. first[B] = E), plus any E%4 remainder
    if (blockIdx.x == 0 && threadIdx.x == 0) {
        for (int j = (Q << 2); j < E; ++j) {    // remainder elements (none when E%4==0)
            const int a = (j == 0) ? -1 : batch[j - 1];
            const int b = batch[j];
            for (int g = a + 1; g <= b; ++g) {
                first_arr[g] = j;
                if (g < B) {
                    int* pk = pack + g * 64;
                    for (int t = 0; t < TSTEPS; ++t) {
                        int jj = j + t; if (jj > E - 1) jj = E - 1;
                        pk[t]      = edge_index[jj];
                        pk[18 + t] = edge_index[E + jj];
                        pk[36 + t] = edge_attr[jj];
                    }
                }
            }
        }
        const int bl = batch[E - 1];
        for (int g = bl + 1; g <= B; ++g) {
            first_arr[g] = E;
            if (g < B) {                        // empty graphs: valid (clamped) ids, cnt=0
                int* pk = pack + g * 64;
                for (int t = 0; t < TSTEPS; ++t) {
                    pk[t]      = edge_index[E - 1];
                    pk[18 + t] = edge_index[E + E - 1];
                    pk[36 + t] = edge_attr[E - 1];
                }
            }
        }
    }
}

// ---------------------------------------------------------------------------
// Kernel B: one WAVE per graph. Lane wl owns gate row wl (r=wl>>4, u=wl&15).
// Memory chain: {weights || first[] || pack} -> x -> compute (2 rounds).
// ---------------------------------------------------------------------------
extern "C" __global__ __launch_bounds__(256, 4)
void tgnn_lstm_main(const float* __restrict__ x,
                    const float* __restrict__ W_ih,
                    const float* __restrict__ W_hh,
                    const float* __restrict__ b_ih,
                    const float* __restrict__ b_hh,
                    const float* __restrict__ W_fc,
                    const float* __restrict__ b_fc,
                    const int* __restrict__ first_arr,
                    const int* __restrict__ pack,
                    float* __restrict__ out,
                    int B)
{
    const int wl  = threadIdx.x & 63;
    const int g   = (blockIdx.x * blockDim.x + threadIdx.x) >> 6;
    const int u   = wl & 15;
    const int r   = wl >> 4;
    const int row = wl;

    // per-lane weights (issued first; everything below overlaps their latency)
    float wih[IN_SIZE], whh[HID];
#pragma unroll
    for (int k = 0; k < IN_SIZE; ++k) wih[k] = W_ih[row * FEAT + k];
#pragma unroll
    for (int v = 0; v < HID; ++v) whh[v] = W_hh[row * HID + v];
    const float bias = b_ih[row] + b_hh[row];
    const float wfc  = W_fc[row];
    const float bfc  = b_fc[r];

    // boundaries + packed edges: independent loads, one latency round
    const int f0 = first_arr[g];
    const int f1 = first_arr[g + 1];
    int cnt = f1 - f0;
    cnt = (cnt < 0) ? 0 : ((cnt > TSTEPS) ? TSTEPS : cnt);

    int n1 = 0, n2 = 0, ea = 0;
    if (wl < TSTEPS) {
        const int* pk = pack + g * 64;
        n1 = pk[wl];
        n2 = pk[18 + wl];
        ea = pk[36 + wl];            // always in [0,7)
    }

    // x gather: lane t holds step t's 11 summed features (one latency round)
    float f[IN_SIZE];
    {
        const float* xa = x + (long)n1 * IN_SIZE;
        const float* xb = x + (long)n2 * IN_SIZE;
#pragma unroll
        for (int k = 0; k < IN_SIZE; ++k) f[k] = xa[k] + xb[k];
    }
    if (wl >= cnt) {
#pragma unroll
        for (int k = 0; k < IN_SIZE; ++k) f[k] = 0.0f;
    }

    // prologue: a_in[t] = bias + x_t . wih_row + onehot-weight (per lane)
    float ain[TSTEPS];
#pragma unroll
    for (int t = 0; t < TSTEPS; ++t) {
        const int eat = __builtin_amdgcn_readlane(ea, t);   // uniform
        const float w1 = W_ih[row * FEAT + IN_SIZE + eat];  // L1-hot (4.6 KB)
        float a = bias + ((t < cnt) ? w1 : 0.0f);
#pragma unroll
        for (int k = 0; k < IN_SIZE; ++k)
            a = fmaf(rl(f[k], t), wih[k], a);
        ain[t] = a;
    }

    // LSTM: per step 16 readlane + 16 FMA + 1 own-gate activation + 3 swizzles
    const float sa = (r == 2) ? -2.0f : -1.0f;   // r==2 -> tanh via 2*sig(2a)-1
    const float ma = (r == 2) ?  2.0f :  1.0f;
    const float oa = (r == 2) ? -1.0f :  0.0f;

    float h = 0.0f, c = 0.0f;
#pragma unroll
    for (int t = 0; t < TSTEPS; ++t) {
        float a;
        if (t == 0) {
            a = ain[0];
        } else {
            float A0 = ain[t], A1 = 0.0f, A2 = 0.0f, A3 = 0.0f;
#pragma unroll
            for (int v = 0; v < HID; v += 4) {
                A0 = fmaf(rl(h, v + 0), whh[v + 0], A0);
                A1 = fmaf(rl(h, v + 1), whh[v + 1], A1);
                A2 = fmaf(rl(h, v + 2), whh[v + 2], A2);
                A3 = fmaf(rl(h, v + 3), whh[v + 3], A3);
            }
            a = (A0 + A1) + (A2 + A3);
        }
        const float act = fmaf(ma, fast_rcp(1.0f + __expf(sa * a)), oa);
        const float s1 = __shfl_xor(act, 16, 64);   // sigma(f)
        const float s2 = __shfl_xor(act, 32, 64);   // tanh(g)
        const float s3 = __shfl_xor(s1, 32, 64);    // sigma(o)
        c = fmaf(s1, c, act * s2);                  // lanes 0..15 valid
        const float th = fmaf(2.0f, fast_rcp(1.0f + __expf(-2.0f * c)), -1.0f);
        h = s3 * th;
    }

    // fc epilogue
    const float hb = __shfl(h, u, 64);
    float p = hb * wfc;
#pragma unroll
    for (int m = 8; m >= 1; m >>= 1) p += __shfl_xor(p, m, 16);
    if (u == 0 && g < B) out[g * 4 + r] = p + bfc;
}

extern "C" void kernel_launch(void* const* d_in, const int* in_sizes, int n_in,
                              void* d_out, int out_size, void* d_ws, size_t ws_size,
                              hipStream_t stream) {
    const float* x     = (const float*)d_in[0];
    const float* W_ih  = (const float*)d_in[1];
    const float* W_hh  = (const float*)d_in[2];
    const float* b_ih  = (const float*)d_in[3];
    const float* b_hh  = (const float*)d_in[4];
    const float* W_fc  = (const float*)d_in[5];
    const float* b_fc  = (const float*)d_in[6];
    const int* edge_index = (const int*)d_in[7];
    const int* edge_attr  = (const int*)d_in[8];
    const int* batch      = (const int*)d_in[9];

    const int E = in_sizes[8];       // N_EDGES
    const int B = out_size / 4;      // N_GRAPHS

    int* first_arr = (int*)d_ws;
    int* pack      = first_arr + PACK_OFF;

    scan_bounds<<<2048, 256, 0, stream>>>(batch, edge_index, edge_attr,
                                          first_arr, pack, E, B);

    const int grid = (B + 3) / 4;    // 4 graphs (waves) per 256-thread block
    tgnn_lstm_main<<<grid, 256, 0, stream>>>(x, W_ih, W_hh, b_ih, b_hh,
                                             W_fc, b_fc, first_arr, pack,
                                             (float*)d_out, B);
}

// Round 6
// 23.629 us; speedup vs baseline: 2.0258x; 2.0258x over previous
//
#include <hip/hip_runtime.h>

#define IN_SIZE 11
#define HID 16
#define FEAT 18
#define TSTEPS 18

__device__ __forceinline__ float fast_rcp(float v) { return __builtin_amdgcn_rcpf(v); }

// broadcast a float from a fixed lane via v_readlane (SGPR path, no DS)
__device__ __forceinline__ float rl(float v, int lane) {
    return __int_as_float(__builtin_amdgcn_readlane(__float_as_int(v), lane));
}

// One WAVE per graph. Lane wl owns gate row wl (r=wl>>4, u=wl&15).
// Search: dual lower_bound in 32-lane halves (lanes 0-31 -> g, 32-63 -> g+1),
// 32-ary wide rounds (top rounds L2-shared across waves) + contiguous 32-elem
// final scan (2-3 cache lines, all bytes used). Then r4's gather + LSTM.
extern "C" __global__ __launch_bounds__(256, 4)
void tgnn_lstm_fused(const float* __restrict__ x,
                     const float* __restrict__ W_ih,
                     const float* __restrict__ W_hh,
                     const float* __restrict__ b_ih,
                     const float* __restrict__ b_hh,
                     const float* __restrict__ W_fc,
                     const float* __restrict__ b_fc,
                     const int* __restrict__ edge_index,
                     const int* __restrict__ edge_attr,
                     const int* __restrict__ batch,
                     float* __restrict__ out,
                     int E, int B)
{
    const int wl  = threadIdx.x & 63;
    const int g   = (blockIdx.x * blockDim.x + threadIdx.x) >> 6;  // wave id = graph
    const int u   = wl & 15;
    const int r   = wl >> 4;
    const int row = wl;

    // ---- per-lane weights (issued first; latency overlaps the search) ----
    float wih[IN_SIZE], whh[HID];
#pragma unroll
    for (int k = 0; k < IN_SIZE; ++k) wih[k] = W_ih[row * FEAT + k];
#pragma unroll
    for (int v = 0; v < HID; ++v) whh[v] = W_hh[row * HID + v];
    const float bias = b_ih[row] + b_hh[row];
    const float wfc  = W_fc[row];
    const float bfc  = b_fc[r];

    // ---- dual lower_bound, 32-lane halves: lanes<32 -> lb(g), >=32 -> lb(g+1) ----
    // invariant: lb in [lo, hi]; round: 32 probes p_l = lo + (n*l)>>5 (prefix of
    // "batch[p]<v" is true); myc = popcount of own half's ballot bits.
    const int vt  = g + (wl >> 5);       // target value for this half
    const int l32 = wl & 31;
    int lo = 0, hi = E;
    int n = hi - lo;
    while (n > 32) {
        const int p  = lo + (int)(((unsigned)n * (unsigned)l32) >> 5);
        const int bv = batch[p];
        const unsigned long long bal = __ballot(bv < vt);
        const int myc = (wl < 32) ? __popc((unsigned)bal)
                                  : __popc((unsigned)(bal >> 32));
        const int nlo = myc ? (lo + (int)(((unsigned)n * (unsigned)(myc - 1)) >> 5) + 1) : lo;
        const int nhi = (myc < 32) ? (lo + (int)(((unsigned)n * (unsigned)myc) >> 5)) : hi;
        lo = nlo; hi = nhi; n = hi - lo;
    }
    {   // final: contiguous scan of [lo, lo+n), n <= 32 (2-3 cache lines)
        int p = lo + l32; if (p > E - 1) p = E - 1;
        const bool lt = (l32 < n) && (batch[p] < vt);
        const unsigned long long bal = __ballot(lt);
        const int myc = (wl < 32) ? __popc((unsigned)bal)
                                  : __popc((unsigned)(bal >> 32));
        lo += myc;                       // = lower_bound(batch, vt)
    }
    const int f0 = __builtin_amdgcn_readlane(lo, 0);    // first edge of g
    const int f1 = __builtin_amdgcn_readlane(lo, 32);   // first edge of g+1
    int cnt = f1 - f0;
    cnt = (cnt < 0) ? 0 : ((cnt > TSTEPS) ? TSTEPS : cnt);

    // ---- edge fetch: lane t (t<18) loads step t's ids + attr (one round) ----
    int n1 = 0, n2 = 0, ea = 0;
    if (wl < TSTEPS) {
        int j = f0 + wl;
        if (j > E - 1) j = E - 1;
        n1 = edge_index[j];
        n2 = edge_index[E + j];
        ea = edge_attr[j];               // in [0,7) even when clamped
    }

    // ---- x gather: lane t holds step t's 11 summed features (one round) ----
    float f[IN_SIZE];
    {
        const float* xa = x + (long)n1 * IN_SIZE;
        const float* xb = x + (long)n2 * IN_SIZE;
#pragma unroll
        for (int k = 0; k < IN_SIZE; ++k) f[k] = xa[k] + xb[k];
    }
    if (wl >= cnt) {                     // invalid steps AND lanes >= 18
#pragma unroll
        for (int k = 0; k < IN_SIZE; ++k) f[k] = 0.0f;
    }

    // ---- prologue: a_in[t] = bias + x_t . wih_row + onehot-weight (per lane) ----
    float ain[TSTEPS];
#pragma unroll
    for (int t = 0; t < TSTEPS; ++t) {
        const int eat = __builtin_amdgcn_readlane(ea, t);   // uniform
        const float w1 = W_ih[row * FEAT + IN_SIZE + eat];  // L1-hot (4.6 KB)
        float a = bias + ((t < cnt) ? w1 : 0.0f);
#pragma unroll
        for (int k = 0; k < IN_SIZE; ++k)
            a = fmaf(rl(f[k], t), wih[k], a);
        ain[t] = a;
    }

    // ---- LSTM: per step 16 readlane + 16 FMA + 1 own-gate act + 3 swizzles ----
    const float sa = (r == 2) ? -2.0f : -1.0f;   // r==2 -> tanh via 2*sig(2a)-1
    const float ma = (r == 2) ?  2.0f :  1.0f;
    const float oa = (r == 2) ? -1.0f :  0.0f;

    float h = 0.0f, c = 0.0f;
#pragma unroll
    for (int t = 0; t < TSTEPS; ++t) {
        float a;
        if (t == 0) {
            a = ain[0];
        } else {
            float A0 = ain[t], A1 = 0.0f, A2 = 0.0f, A3 = 0.0f;
#pragma unroll
            for (int v = 0; v < HID; v += 4) {
                A0 = fmaf(rl(h, v + 0), whh[v + 0], A0);
                A1 = fmaf(rl(h, v + 1), whh[v + 1], A1);
                A2 = fmaf(rl(h, v + 2), whh[v + 2], A2);
                A3 = fmaf(rl(h, v + 3), whh[v + 3], A3);
            }
            a = (A0 + A1) + (A2 + A3);
        }
        const float act = fmaf(ma, fast_rcp(1.0f + __expf(sa * a)), oa);
        const float s1 = __shfl_xor(act, 16, 64);   // sigma(f)
        const float s2 = __shfl_xor(act, 32, 64);   // tanh(g)
        const float s3 = __shfl_xor(s1, 32, 64);    // sigma(o)
        c = fmaf(s1, c, act * s2);                  // lanes 0..15 valid
        const float th = fmaf(2.0f, fast_rcp(1.0f + __expf(-2.0f * c)), -1.0f);
        h = s3 * th;
    }

    // ---- fc epilogue ----
    const float hb = __shfl(h, u, 64);              // lane wl <- h[u] from lane u
    float p = hb * wfc;                             // W_fc[r][u] == W_fc[row]
#pragma unroll
    for (int m = 8; m >= 1; m >>= 1) p += __shfl_xor(p, m, 16);
    if (u == 0 && g < B) out[g * 4 + r] = p + bfc;
}

extern "C" void kernel_launch(void* const* d_in, const int* in_sizes, int n_in,
                              void* d_out, int out_size, void* d_ws, size_t ws_size,
                              hipStream_t stream) {
    const float* x     = (const float*)d_in[0];
    const float* W_ih  = (const float*)d_in[1];
    const float* W_hh  = (const float*)d_in[2];
    const float* b_ih  = (const float*)d_in[3];
    const float* b_hh  = (const float*)d_in[4];
    const float* W_fc  = (const float*)d_in[5];
    const float* b_fc  = (const float*)d_in[6];
    const int* edge_index = (const int*)d_in[7];
    const int* edge_attr  = (const int*)d_in[8];
    const int* batch      = (const int*)d_in[9];

    const int E = in_sizes[8];       // N_EDGES
    const int B = out_size / 4;      // N_GRAPHS

    const int grid = (B + 3) / 4;    // 4 graphs (waves) per 256-thread block
    tgnn_lstm_fused<<<grid, 256, 0, stream>>>(x, W_ih, W_hh, b_ih, b_hh,
                                              W_fc, b_fc,
                                              edge_index, edge_attr, batch,
                                              (float*)d_out, E, B);
}